// Round 5
// baseline (1838.992 us; speedup 1.0000x reference)
//
#include <hip/hip_runtime.h>

#define TT 512
#define BB 16
#define DD 256
#define HHH 128
#define GG 32
#define ZZ 8
#define RR_ 16
#define NAA 18

typedef __attribute__((ext_vector_type(8))) short short8;
typedef __attribute__((ext_vector_type(4))) float f32x4;

__device__ __forceinline__ float sigmoid_(float x) { return 1.f / (1.f + __expf(-x)); }
__device__ __forceinline__ float tanh_(float x) { float e = __expf(2.f * x); return 1.f - 2.f / (e + 1.f); }
__device__ __forceinline__ float dot4(float4 a, float4 b) {
    return a.x * b.x + a.y * b.y + a.z * b.z + a.w * b.w;
}
__device__ __forceinline__ unsigned short bf16r(float x) {
    unsigned u = __float_as_uint(x);
    return (unsigned short)((u + 0x7FFFu + ((u >> 16) & 1u)) >> 16);
}

// ---------------------------------------------------------------------------
// Generic tiled GEMM. mode: 0 = store, 1 = accumulate,
// 2 = store transposed for the GRU: Out[(t*384 + n)*16 + b], row = b*512+t.
// ---------------------------------------------------------------------------
__global__ __launch_bounds__(256) void gemm_k(
    const float* __restrict__ A, int K, const float* __restrict__ W, int ldw,
    const float* __restrict__ bias, float* __restrict__ Out, int ldout, int N, int mode)
{
    __shared__ float At[64][33];
    __shared__ float Wt[32][33];
    int row0 = blockIdx.x * 64, n0 = blockIdx.y * 32;
    int tid = threadIdx.x;
    int tx = tid & 15, ty = tid >> 4;
    float acc[4][2] = {};
    for (int k0 = 0; k0 < K; k0 += 32) {
        #pragma unroll
        for (int i = 0; i < 8; ++i) {
            int idx = tid + i * 256; int rr = idx >> 5, kk = idx & 31;
            At[rr][kk] = A[(size_t)(row0 + rr) * K + k0 + kk];
        }
        #pragma unroll
        for (int i = 0; i < 4; ++i) {
            int idx = tid + i * 256; int nn = idx >> 5, kk = idx & 31;
            Wt[nn][kk] = (n0 + nn < N) ? W[(size_t)(n0 + nn) * ldw + k0 + kk] : 0.f;
        }
        __syncthreads();
        #pragma unroll
        for (int kk = 0; kk < 32; ++kk) {
            float w0 = Wt[tx][kk], w1 = Wt[tx + 16][kk];
            #pragma unroll
            for (int rr = 0; rr < 4; ++rr) {
                float av = At[ty * 4 + rr][kk];
                acc[rr][0] += av * w0;
                acc[rr][1] += av * w1;
            }
        }
        __syncthreads();
    }
    #pragma unroll
    for (int cc = 0; cc < 2; ++cc) {
        int n = n0 + tx + cc * 16;
        if (n < N) {
            float badd = bias ? bias[n] : 0.f;
            #pragma unroll
            for (int rr = 0; rr < 4; ++rr) {
                int row = row0 + ty * 4 + rr;
                float v = acc[rr][cc] + badd;
                if (mode == 1)      Out[(size_t)row * ldout + n] += v;
                else if (mode == 2) {
                    int bq = row >> 9, tq = row & 511;
                    Out[((size_t)tq * 384 + n) * 16 + bq] = v;
                } else              Out[(size_t)row * ldout + n] = v;
            }
        }
    }
}

// ---------------------------------------------------------------------------
// Bidirectional GRU recurrence via MFMA. Grid = 2 (one WG per direction),
// 512 threads = 8 waves (2/SIMD). Per step: gh(16x384) = h(16x128) @ W^T
// with mfma_f32_16x16x32_bf16, W split hi+lo (2 MFMA terms -> only h's
// bf16 rounding remains). Wave w owns gate-aligned n-tiles {w, 8+w, 16+w}
// so each lane holds r,z,n accumulators for its own (batch-quad, hidden j)
// -> gates computed fully in-lane, h fp32 persists in lane registers.
// h_hi staged in double-buffered LDS as ready-made A-fragments.
// gi is read in the [t][384][16] transposed layout (gemm mode 2).
// ---------------------------------------------------------------------------
__global__ __launch_bounds__(512, 2) void gru_seq(
    const float* __restrict__ gi_f, const float* __restrict__ gi_b,
    const float* __restrict__ whh_f, const float* __restrict__ bhh_f,
    const float* __restrict__ whh_b, const float* __restrict__ bhh_b,
    float* __restrict__ s_seq)
{
    int dir = blockIdx.x;
    const float* gi  = dir ? gi_b  : gi_f;
    const float* whh = dir ? whh_b : whh_f;
    const float* bhh = dir ? bhh_b : bhh_f;
    int tid = threadIdx.x;
    int w = tid >> 6;          // wave 0..7
    int L = tid & 63;
    int c = L & 15;            // tile column (gate j) / batch m for A-frag read
    int q = L >> 4;            // quad
    int j = 16 * w + c;        // hidden unit owned by this lane for gates

    // B-fragments: B[k][n] = W[n][k]; lane element jj -> k = kt*32 + q*8 + jj,
    // n = n0 + c. Tiles: T=0 -> n0=16w (r), T=1 -> 128+16w (z), T=2 -> 256+16w (n).
    short8 whi[3][4], wlo[3][4];
    #pragma unroll
    for (int T = 0; T < 3; ++T) {
        const float* wrow = whh + (size_t)(T * 128 + j) * 128;
        #pragma unroll
        for (int kt = 0; kt < 4; ++kt) {
            union { short8 v; unsigned short e[8]; } hi, lo;
            #pragma unroll
            for (int jj = 0; jj < 8; ++jj) {
                float x = wrow[kt * 32 + q * 8 + jj];
                unsigned short h16 = bf16r(x);
                float xh = __uint_as_float(((unsigned)h16) << 16);
                hi.e[jj] = (short)h16;
                lo.e[jj] = (short)bf16r(x - xh);
            }
            whi[T][kt] = hi.v; wlo[T][kt] = lo.v;
        }
    }
    float bhr = bhh[j], bhz = bhh[128 + j], bhn = bhh[256 + j];
    float hp[4] = {0.f, 0.f, 0.f, 0.f};

    // h_hi staging as A-fragments: [buf][kt][m][q][jj]  (2 x 4KB)
    __shared__ unsigned short hfrag[2][4][16][4][8];
    for (int u = tid; u < 2048; u += 512) ((unsigned short*)hfrag)[u] = 0;
    __syncthreads();

    int cb = 0;
    for (int t = 0; t < 512; ++t) {
        int tt = dir ? (511 - t) : t;
        // A-fragments: lane needs h[m=c][k = kt*32 + q*8 + jj]
        short8 a[4];
        #pragma unroll
        for (int kt = 0; kt < 4; ++kt)
            a[kt] = *(const short8*)&hfrag[cb][kt][c][q][0];
        // gi loads issued early (consumed after MFMA): components i -> batch 4q+i
        const float4 gir = *(const float4*)(gi + ((size_t)tt * 384 + j) * 16 + 4 * q);
        const float4 giz = *(const float4*)(gi + ((size_t)tt * 384 + 128 + j) * 16 + 4 * q);
        const float4 gin = *(const float4*)(gi + ((size_t)tt * 384 + 256 + j) * 16 + 4 * q);

        f32x4 accr = {0.f, 0.f, 0.f, 0.f};
        f32x4 accz = {0.f, 0.f, 0.f, 0.f};
        f32x4 accn = {0.f, 0.f, 0.f, 0.f};
        #pragma unroll
        for (int kt = 0; kt < 4; ++kt) {
            accr = __builtin_amdgcn_mfma_f32_16x16x32_bf16(a[kt], whi[0][kt], accr, 0, 0, 0);
            accz = __builtin_amdgcn_mfma_f32_16x16x32_bf16(a[kt], whi[1][kt], accz, 0, 0, 0);
            accn = __builtin_amdgcn_mfma_f32_16x16x32_bf16(a[kt], whi[2][kt], accn, 0, 0, 0);
            accr = __builtin_amdgcn_mfma_f32_16x16x32_bf16(a[kt], wlo[0][kt], accr, 0, 0, 0);
            accz = __builtin_amdgcn_mfma_f32_16x16x32_bf16(a[kt], wlo[1][kt], accz, 0, 0, 0);
            accn = __builtin_amdgcn_mfma_f32_16x16x32_bf16(a[kt], wlo[2][kt], accn, 0, 0, 0);
        }
        // gates: lane holds D[m = 4q+i][n] for its j; all three gates in-lane
        #pragma unroll
        for (int i = 0; i < 4; ++i) {
            float r = sigmoid_((&gir.x)[i] + bhr + accr[i]);
            float z = sigmoid_((&giz.x)[i] + bhz + accz[i]);
            float n = tanh_((&gin.x)[i] + r * (bhn + accn[i]));
            float h = (1.f - z) * n + z * hp[i];
            hp[i] = h;
            int m = 4 * q + i;
            s_seq[((size_t)(m * 512 + tt)) * 256 + dir * 128 + j] = h;
            hfrag[cb ^ 1][j >> 5][m][(j >> 3) & 3][j & 7] = bf16r(h);
        }
        __syncthreads();
        cb ^= 1;
    }
}

// ---------------------------------------------------------------------------
// Controller h-scan. 16 WGs, 128 threads (2 waves).
// ---------------------------------------------------------------------------
__global__ __launch_bounds__(128, 1) void ctrl_h_scan(
    const float* __restrict__ gie, const float* __restrict__ whh_e,
    const float* __restrict__ bhh_e, float* __restrict__ h_seq)
{
    int b = blockIdx.x, tid = threadIdx.x;
    float4 w[8] = {};
    float bias = 0.f;
    if (tid < 96) {
        const float4* wp = (const float4*)(whh_e + (size_t)tid * 32);
        #pragma unroll
        for (int i = 0; i < 8; ++i) w[i] = wp[i];
        bias = bhh_e[tid];
    }
    __shared__ __align__(16) float hbuf[32];
    __shared__ float ghl[96];
    if (tid < 32) hbuf[tid] = 0.f;

    int pbase = b * TT;
    float g1a = 0.f, g2a = 0.f, g3a = 0.f, g1b = 0.f, g2b = 0.f, g3b = 0.f;
    float hreg = 0.f;
    if (tid < 32) {
        size_t p0 = (size_t)pbase * 96, p1 = (size_t)(pbase + 1) * 96;
        g1a = gie[p0 + tid]; g2a = gie[p0 + 32 + tid]; g3a = gie[p0 + 64 + tid];
        g1b = gie[p1 + tid]; g2b = gie[p1 + 32 + tid]; g3b = gie[p1 + 64 + tid];
    }
    __syncthreads();

    auto body = [&](int t, float& g1, float& g2, float& g3) {
        if (tid < 96) {
            const float4* hv = (const float4*)hbuf;
            float gh = bias;
            #pragma unroll
            for (int i = 0; i < 8; ++i) gh += dot4(w[i], hv[i]);
            ghl[tid] = gh;
        }
        __syncthreads();
        if (tid < 32) {
            float r = sigmoid_(g1 + ghl[tid]);
            float z = sigmoid_(g2 + ghl[32 + tid]);
            float n = tanh_(g3 + r * ghl[64 + tid]);
            float hn = (1.f - z) * n + z * hreg;
            hreg = hn;
            hbuf[tid] = hn;
            h_seq[(size_t)(pbase + t) * 32 + tid] = hn;
            int t2 = (t + 2 < 512) ? t + 2 : t;
            size_t p2 = (size_t)(pbase + t2) * 96;
            g1 = gie[p2 + tid]; g2 = gie[p2 + 32 + tid]; g3 = gie[p2 + 64 + tid];
        }
        __syncthreads();
    };

    for (int t = 0; t < 512; t += 2) {
        body(t,     g1a, g2a, g3a);
        body(t + 1, g1b, g2b, g3b);
    }
}

// ---------------------------------------------------------------------------
// Controller z/beta scan. 16 WGs, 1 wave, no LDS, no barriers.
// ---------------------------------------------------------------------------
__global__ __launch_bounds__(64, 1) void ctrl_z_scan(
    const float* __restrict__ hid_pre, const float* __restrict__ sw1_w,
    const float* __restrict__ sw2_w, const float* __restrict__ sw2_b,
    const float* __restrict__ eps, const float* __restrict__ mu_o,
    const float* __restrict__ lv_o, float* __restrict__ beta_o, float* __restrict__ z_o)
{
    int b = blockIdx.x, q = threadIdx.x;
    float wz[8];
    #pragma unroll
    for (int x = 0; x < 8; ++x) wz[x] = sw1_w[(size_t)q * 296 + 288 + x];
    float w2 = sw2_w[q];
    float bb = sw2_b[0];
    float zc = 0.f;
    int pbase = b * TT;

    float hpa = hid_pre[(size_t)pbase * 64 + q];
    float hpb = hid_pre[(size_t)(pbase + 1) * 64 + q];
    float mua = 0.f, lva = 0.f, epa = 0.f, mub = 0.f, lvb = 0.f, epb = 0.f;
    if (q < 8) {
        mua = mu_o[pbase * 8 + q]; lva = lv_o[pbase * 8 + q]; epa = eps[pbase * 8 + q];
        mub = mu_o[(pbase + 1) * 8 + q]; lvb = lv_o[(pbase + 1) * 8 + q]; epb = eps[(pbase + 1) * 8 + q];
    }

    auto body = [&](int t, float& hp, float& mu, float& lv, float& ep) {
        int p = pbase + t;
        float a = hp;
        #pragma unroll
        for (int x = 0; x < 8; ++x) a += wz[x] * __shfl(zc, x);
        float hid = tanh_(a);
        float prod = w2 * hid;
        #pragma unroll
        for (int m = 32; m >= 1; m >>= 1) prod += __shfl_xor(prod, m);
        float beta = sigmoid_(prod + bb);
        float zn = beta * (mu + __expf(0.5f * lv) * ep) + (1.f - beta) * zc;
        zc = zn;                      // meaningful in lanes 0-7 only
        if (q < 8) z_o[p * 8 + q] = zn;
        if (q == 0) beta_o[p] = beta;
        int t2 = (t + 2 < 512) ? t + 2 : t;
        hp = hid_pre[(size_t)(pbase + t2) * 64 + q];
        if (q < 8) {
            mu = mu_o[(pbase + t2) * 8 + q];
            lv = lv_o[(pbase + t2) * 8 + q];
            ep = eps[(pbase + t2) * 8 + q];
        }
    };

    for (int t = 0; t < 512; t += 2) {
        body(t,     hpa, mua, lva, epa);
        body(t + 1, hpb, mub, lvb, epb);
    }
}

// ---------------------------------------------------------------------------
// Decoder hypernet + rank-R perturbation + LayerNorm + head. P=8/WG.
// ---------------------------------------------------------------------------
__global__ __launch_bounds__(256, 3) void decoder_final(
    const float* __restrict__ e_seq, const float* __restrict__ z_o,
    const float* __restrict__ dec1_w, const float* __restrict__ dec1_b,
    const float* __restrict__ dec2_w, const float* __restrict__ dec2_b,
    const float* __restrict__ ln_g, const float* __restrict__ ln_b,
    const float* __restrict__ head_w, const float* __restrict__ head_b,
    float* __restrict__ logits)
{
    __shared__ __align__(16) float e_l[8][256];
    __shared__ __align__(16) float hmid[8][32];
    __shared__ float zl[8][8];
    __shared__ float tmpw[8][16];
    __shared__ __align__(16) float partb[2048];
    __shared__ float red1[8][16];
    __shared__ float red2[8][16];
    __shared__ float stats[8][2];
    int tid = threadIdx.x;
    int p0 = blockIdx.x * 8;

    {
        const float4* eg = (const float4*)(e_seq + (size_t)p0 * 256);
        float4* el4 = (float4*)&e_l[0][0];
        el4[tid] = eg[tid];
        el4[tid + 256] = eg[tid + 256];
        if (tid < 64) ((float*)zl)[tid] = z_o[p0 * 8 + tid];
    }
    __syncthreads();
    {
        int pp = tid >> 5, g = tid & 31;
        float a = dec1_b[g];
        #pragma unroll
        for (int x = 0; x < 8; ++x) a += dec1_w[g * 8 + x] * zl[pp][x];
        hmid[pp][g] = tanh_(a);
    }
    __syncthreads();
    // ---- pass B: tmp[pp][r] = sum_d Bm[d,r]*e[d]
    {
        int r = tid & 15, dgrp = tid >> 4;
        float acc[8];
        #pragma unroll
        for (int pp = 0; pp < 8; ++pp) acc[pp] = 0.f;
        for (int iblk = 0; iblk < 8; ++iblk) {
            float4 wr[2][8]; float wb[2]; int dd[2];
            #pragma unroll
            for (int ii = 0; ii < 2; ++ii) {
                int d = dgrp + 16 * (iblk * 2 + ii);
                dd[ii] = d;
                int row = 4096 + d * 16 + r;
                const float4* wp = (const float4*)(dec2_w + (size_t)row * 32);
                #pragma unroll
                for (int g = 0; g < 8; ++g) wr[ii][g] = wp[g];
                wb[ii] = dec2_b[row];
            }
            #pragma unroll 1
            for (int pp = 0; pp < 8; ++pp) {
                const float4* hv = (const float4*)hmid[pp];
                float b0 = wb[0], b1 = wb[1];
                #pragma unroll
                for (int g = 0; g < 8; ++g) {
                    float4 hh = hv[g];
                    b0 += dot4(wr[0][g], hh);
                    b1 += dot4(wr[1][g], hh);
                }
                acc[pp] += b0 * e_l[pp][dd[0]] + b1 * e_l[pp][dd[1]];
            }
        }
        #pragma unroll
        for (int pp = 0; pp < 8; ++pp) partb[(pp * 16 + r) * 16 + dgrp] = acc[pp];
    }
    __syncthreads();
    if (tid < 128) {
        int pp = tid >> 4, rr = tid & 15;
        float s = 0.f;
        #pragma unroll
        for (int dg = 0; dg < 16; ++dg) s += partb[(pp * 16 + rr) * 16 + dg];
        tmpw[pp][rr] = s;
    }
    __syncthreads();
    // ---- pass A
    {
        int d = tid;
        float po[8];
        #pragma unroll
        for (int pp = 0; pp < 8; ++pp) po[pp] = e_l[pp][d];
        for (int rblk = 0; rblk < 8; ++rblk) {
            float4 wr[2][8]; float wb[2];
            #pragma unroll
            for (int ii = 0; ii < 2; ++ii) {
                int row = d * 16 + rblk * 2 + ii;
                const float4* wp = (const float4*)(dec2_w + (size_t)row * 32);
                #pragma unroll
                for (int g = 0; g < 8; ++g) wr[ii][g] = wp[g];
                wb[ii] = dec2_b[row];
            }
            #pragma unroll 1
            for (int pp = 0; pp < 8; ++pp) {
                const float4* hv = (const float4*)hmid[pp];
                float a0 = wb[0], a1 = wb[1];
                #pragma unroll
                for (int g = 0; g < 8; ++g) {
                    float4 hh = hv[g];
                    a0 += dot4(wr[0][g], hh);
                    a1 += dot4(wr[1][g], hh);
                }
                po[pp] += a0 * tmpw[pp][rblk * 2] + a1 * tmpw[pp][rblk * 2 + 1];
            }
        }
        #pragma unroll
        for (int pp = 0; pp < 8; ++pp) partb[pp * 256 + d] = po[pp];
    }
    __syncthreads();
    if (tid < 128) {
        int pp = tid >> 4, c = tid & 15;
        float s = 0.f, s2 = 0.f;
        #pragma unroll
        for (int i = 0; i < 16; ++i) { float v = partb[pp * 256 + c * 16 + i]; s += v; s2 += v * v; }
        red1[pp][c] = s; red2[pp][c] = s2;
    }
    __syncthreads();
    if (tid < 8) {
        float s = 0.f, s2 = 0.f;
        #pragma unroll
        for (int c = 0; c < 16; ++c) { s += red1[tid][c]; s2 += red2[tid][c]; }
        float mean = s * (1.f / 256.f);
        float var = s2 * (1.f / 256.f) - mean * mean;
        stats[tid][0] = mean;
        stats[tid][1] = rsqrtf(var + 1e-5f);
    }
    __syncthreads();
    {
        int d = tid;
        float g = ln_g[d], bln = ln_b[d];
        #pragma unroll
        for (int pp = 0; pp < 8; ++pp) {
            float v = (partb[pp * 256 + d] - stats[pp][0]) * stats[pp][1];
            partb[pp * 256 + d] = v * g + bln;
        }
    }
    __syncthreads();
    if (tid < 144) {
        int pp = tid / 18, na = tid - pp * 18;
        float a = head_b[na];
        for (int d2 = 0; d2 < 256; ++d2)
            a += partb[pp * 256 + d2] * head_w[na * 256 + d2];
        logits[(size_t)(p0 + pp) * 18 + na] = a;
    }
}

// ---------------------------------------------------------------------------
extern "C" void kernel_launch(void* const* d_in, const int* in_sizes, int n_in,
                              void* d_out, int out_size, void* d_ws, size_t ws_size,
                              hipStream_t stream) {
    (void)in_sizes; (void)n_in; (void)out_size; (void)ws_size;
    const float* e     = (const float*)d_in[0];
    const float* eps   = (const float*)d_in[1];
    const float* wih_f = (const float*)d_in[2];
    const float* whh_f = (const float*)d_in[3];
    const float* bih_f = (const float*)d_in[4];
    const float* bhh_f = (const float*)d_in[5];
    const float* wih_b = (const float*)d_in[6];
    const float* whh_b = (const float*)d_in[7];
    const float* bih_b = (const float*)d_in[8];
    const float* bhh_b = (const float*)d_in[9];
    const float* wih_e = (const float*)d_in[10];
    const float* whh_e = (const float*)d_in[11];
    const float* bih_e = (const float*)d_in[12];
    const float* bhh_e = (const float*)d_in[13];
    const float* mu_w  = (const float*)d_in[14];
    const float* mu_b  = (const float*)d_in[15];
    const float* lv_w  = (const float*)d_in[16];
    const float* lv_b  = (const float*)d_in[17];
    const float* sw1_w = (const float*)d_in[18];
    const float* sw1_b = (const float*)d_in[19];
    const float* sw2_w = (const float*)d_in[20];
    const float* sw2_b = (const float*)d_in[21];
    const float* dec1_w = (const float*)d_in[22];
    const float* dec1_b = (const float*)d_in[23];
    const float* dec2_w = (const float*)d_in[24];
    const float* dec2_b = (const float*)d_in[25];
    const float* ln_g  = (const float*)d_in[26];
    const float* ln_b  = (const float*)d_in[27];
    const float* head_w = (const float*)d_in[28];
    const float* head_b = (const float*)d_in[29];

    float* ws    = (float*)d_ws;
    float* gi_f  = ws;                       // 8192*384 (layout [t][384][16])
    float* gi_b  = gi_f + 3145728;           // 8192*384 (layout [t][384][16])
    float* gie   = gi_b + 3145728;           // 8192*96
    float* swe   = gie + 786432;             // 8192*64 (hid_pre)
    float* s_seq = swe + 524288;             // 8192*256
    float* h_seq = s_seq + 2097152;          // 8192*32

    float* out       = (float*)d_out;
    float* out_logit = out;                  // 147456
    float* out_mu    = out + 147456;         // 65536
    float* out_lv    = out + 212992;         // 65536
    float* out_beta  = out + 278528;         // 8192
    float* out_z     = out + 286720;         // 65536

    // input projections (parallel); gi_f/gi_b in GRU-transposed layout
    gemm_k<<<dim3(128, 12), 256, 0, stream>>>(e, 256, wih_f, 256, bih_f, gi_f, 384, 384, 2);
    gemm_k<<<dim3(128, 12), 256, 0, stream>>>(e, 256, wih_b, 256, bih_b, gi_b, 384, 384, 2);
    gemm_k<<<dim3(128, 3),  256, 0, stream>>>(e, 256, wih_e, 512, bih_e, gie, 96, 96, 0);
    gemm_k<<<dim3(128, 2),  256, 0, stream>>>(e, 256, sw1_w, 296, sw1_b, swe, 64, 64, 0);
    // bidirectional GRU recurrence (MFMA, one WG per direction)
    gru_seq<<<2, 512, 0, stream>>>(gi_f, gi_b, whh_f, bhh_f, whh_b, bhh_b, s_seq);
    // add s-part of controller GRU input projection
    gemm_k<<<dim3(128, 3), 256, 0, stream>>>(s_seq, 256, wih_e + 256, 512, nullptr, gie, 96, 96, 1);
    // controller h scan
    ctrl_h_scan<<<16, 128, 0, stream>>>(gie, whh_e, bhh_e, h_seq);
    // mu / logvar heads + h-part of switching-unit input
    gemm_k<<<dim3(128, 1), 256, 0, stream>>>(h_seq, 32, mu_w, 32, mu_b, out_mu, 8, 8, 0);
    gemm_k<<<dim3(128, 1), 256, 0, stream>>>(h_seq, 32, lv_w, 32, lv_b, out_lv, 8, 8, 0);
    gemm_k<<<dim3(128, 2), 256, 0, stream>>>(h_seq, 32, sw1_w + 256, 296, nullptr, swe, 64, 64, 1);
    // beta / z scan
    ctrl_z_scan<<<16, 64, 0, stream>>>(swe, sw1_w, sw2_w, sw2_b, eps, out_mu, out_lv, out_beta, out_z);
    // decoder hypernet + perturbation + LN + head
    decoder_final<<<1024, 256, 0, stream>>>(e, out_z, dec1_w, dec1_b, dec2_w, dec2_b,
                                            ln_g, ln_b, head_w, head_b, out_logit);
}

// Round 6
// 1413.765 us; speedup vs baseline: 1.3008x; 1.3008x over previous
//
#include <hip/hip_runtime.h>

#define TT 512
#define BB 16
#define DD 256
#define HHH 128
#define GG 32
#define ZZ 8
#define RR_ 16
#define NAA 18

__device__ __forceinline__ float sigmoid_(float x) { return 1.f / (1.f + __expf(-x)); }
__device__ __forceinline__ float tanh_(float x) { float e = __expf(2.f * x); return 1.f - 2.f / (e + 1.f); }
__device__ __forceinline__ float dot4(float4 a, float4 b) {
    return a.x * b.x + a.y * b.y + a.z * b.z + a.w * b.w;
}
__device__ __forceinline__ unsigned short bf16r(float x) {
    unsigned u = __float_as_uint(x);
    return (unsigned short)((u + 0x7FFFu + ((u >> 16) & 1u)) >> 16);
}
__device__ __forceinline__ float bflo(unsigned u) { return __uint_as_float(u << 16); }
__device__ __forceinline__ float bfhi(unsigned u) { return __uint_as_float(u & 0xFFFF0000u); }

// ---------------------------------------------------------------------------
// Pack recurrent GRU weights to bf16 in per-thread-contiguous layout:
// pk[dir][s][q][j][kk] = bf16(W_dir[3q+j][32s+kk]),  s:k-quarter, q:row-triple.
// ---------------------------------------------------------------------------
__global__ __launch_bounds__(256) void pack_w(
    const float* __restrict__ wf, const float* __restrict__ wb,
    unsigned short* __restrict__ pk)
{
    int i = blockIdx.x * 256 + threadIdx.x;          // 0 .. 98303
    int dir = i / 49152; int r = i % 49152;
    int s = r / 12288;   int rem = r % 12288;
    int q = rem / 96;    int e = rem % 96;
    int j = e / 32;      int kk = e % 32;
    const float* w = dir ? wb : wf;
    pk[i] = bf16r(w[(3 * q + j) * 128 + 32 * s + kk]);
}

// ---------------------------------------------------------------------------
// Generic tiled GEMM: Out[p][n] (+)= bias[n] + sum_k A[p*K+k] * W[n*ldw+k]
// ---------------------------------------------------------------------------
__global__ __launch_bounds__(256) void gemm_k(
    const float* __restrict__ A, int K, const float* __restrict__ W, int ldw,
    const float* __restrict__ bias, float* __restrict__ Out, int ldout, int N, int accFlag)
{
    __shared__ float At[64][33];
    __shared__ float Wt[32][33];
    int row0 = blockIdx.x * 64, n0 = blockIdx.y * 32;
    int tid = threadIdx.x;
    int tx = tid & 15, ty = tid >> 4;
    float acc[4][2] = {};
    for (int k0 = 0; k0 < K; k0 += 32) {
        #pragma unroll
        for (int i = 0; i < 8; ++i) {
            int idx = tid + i * 256; int rr = idx >> 5, kk = idx & 31;
            At[rr][kk] = A[(size_t)(row0 + rr) * K + k0 + kk];
        }
        #pragma unroll
        for (int i = 0; i < 4; ++i) {
            int idx = tid + i * 256; int nn = idx >> 5, kk = idx & 31;
            Wt[nn][kk] = (n0 + nn < N) ? W[(size_t)(n0 + nn) * ldw + k0 + kk] : 0.f;
        }
        __syncthreads();
        #pragma unroll
        for (int kk = 0; kk < 32; ++kk) {
            float w0 = Wt[tx][kk], w1 = Wt[tx + 16][kk];
            #pragma unroll
            for (int rr = 0; rr < 4; ++rr) {
                float av = At[ty * 4 + rr][kk];
                acc[rr][0] += av * w0;
                acc[rr][1] += av * w1;
            }
        }
        __syncthreads();
    }
    #pragma unroll
    for (int cc = 0; cc < 2; ++cc) {
        int n = n0 + tx + cc * 16;
        if (n < N) {
            float badd = bias ? bias[n] : 0.f;
            #pragma unroll
            for (int rr = 0; rr < 4; ++rr) {
                int row = row0 + ty * 4 + rr;
                float v = acc[rr][cc] + badd;
                if (accFlag) Out[(size_t)row * ldout + n] += v;
                else         Out[(size_t)row * ldout + n] = v;
            }
        }
    }
}

// ---------------------------------------------------------------------------
// Bidirectional GRU recurrence. 32 WGs = (dir,b). 512 threads (8 waves,
// 2/SIMD). Thread = (k-quarter s in 0..3) x (rows 3q..3q+2). Recurrent
// weights streamed as bf16 (96 KB/step instead of 192 KB fp32 — the scan
// was L2/L3 weight-bandwidth-bound; R2/R3 both pinned at 426 us). Gates,
// h, accumulation all fp32. 2 barriers/step, gi prefetch depth-2.
// ---------------------------------------------------------------------------
__global__ __launch_bounds__(512, 2) void gru_seq(
    const float* __restrict__ gi_f, const float* __restrict__ gi_b,
    const unsigned short* __restrict__ pk,
    const float* __restrict__ bhh_f, const float* __restrict__ bhh_b,
    float* __restrict__ s_seq)
{
    int bx = blockIdx.x;
    int dir = bx >> 4, b = bx & 15;
    const float* gi  = dir ? gi_b  : gi_f;
    const float* bhh = dir ? bhh_b : bhh_f;
    int tid = threadIdx.x;
    int s = tid >> 7;            // k-quarter (32 wide)
    int q = tid & 127;           // row-triple: rows 3q..3q+2

    const uint4* wv4 = (const uint4*)(pk + ((size_t)(dir * 4 + s) * 128 + q) * 96);

    __shared__ __align__(16) float hb[128];
    __shared__ float part[4 * 384];
    if (tid < 128) hb[tid] = 0.f;

    int k = tid;                 // gate-thread hidden index (tid < 128)
    float bhr = 0.f, bhz = 0.f, bhn = 0.f;
    float gra = 0.f, gza = 0.f, gna = 0.f;
    float grb = 0.f, gzb = 0.f, gnb = 0.f;
    float hreg = 0.f;
    if (tid < 128) {
        bhr = bhh[k]; bhz = bhh[128 + k]; bhn = bhh[256 + k];
        int t0 = dir ? 511 : 0;
        int t1 = dir ? 510 : 1;
        size_t p0 = (size_t)(b * TT + t0) * 384;
        size_t p1 = (size_t)(b * TT + t1) * 384;
        gra = gi[p0 + k]; gza = gi[p0 + 128 + k]; gna = gi[p0 + 256 + k];
        grb = gi[p1 + k]; gzb = gi[p1 + 128 + k]; gnb = gi[p1 + 256 + k];
    }
    __syncthreads();

    auto body = [&](int step, float& gr, float& gz, float& gn) {
        // h slice for this k-quarter: 32 floats (LDS broadcast within quarter)
        const float4* hv = (const float4*)(hb + s * 32);
        float4 h4[8];
        #pragma unroll
        for (int i = 0; i < 8; ++i) h4[i] = hv[i];
        float a0 = 0.f, a1 = 0.f, a2 = 0.f;
        #pragma unroll
        for (int j = 0; j < 3; ++j) {
            float aj = 0.f;
            #pragma unroll
            for (int kb = 0; kb < 4; ++kb) {
                uint4 u = wv4[j * 4 + kb];
                float4 hA = h4[2 * kb];
                float4 hB = h4[2 * kb + 1];
                aj += bflo(u.x) * hA.x + bfhi(u.x) * hA.y
                    + bflo(u.y) * hA.z + bfhi(u.y) * hA.w
                    + bflo(u.z) * hB.x + bfhi(u.z) * hB.y
                    + bflo(u.w) * hB.z + bfhi(u.w) * hB.w;
            }
            if (j == 0) a0 = aj; else if (j == 1) a1 = aj; else a2 = aj;
        }
        int rb = s * 384 + q * 3;
        part[rb] = a0; part[rb + 1] = a1; part[rb + 2] = a2;
        __syncthreads();

        if (tid < 128) {
            int t = dir ? (511 - step) : step;
            int p = b * TT + t;
            float ghr = bhr + part[k]       + part[384 + k]       + part[768 + k]       + part[1152 + k];
            float ghz = bhz + part[128 + k] + part[384 + 128 + k] + part[768 + 128 + k] + part[1152 + 128 + k];
            float ghn = bhn + part[256 + k] + part[384 + 256 + k] + part[768 + 256 + k] + part[1152 + 256 + k];
            float r = sigmoid_(gr + ghr);
            float z = sigmoid_(gz + ghz);
            float n = tanh_(gn + r * ghn);
            float hn = (1.f - z) * n + z * hreg;
            hreg = hn;
            hb[k] = hn;
            s_seq[(size_t)p * 256 + dir * 128 + k] = hn;
            int s2 = step + 2;
            int tp = (s2 < 512) ? (dir ? (511 - s2) : s2) : t;
            size_t p2 = (size_t)(b * TT + tp) * 384;
            gr = gi[p2 + k]; gz = gi[p2 + 128 + k]; gn = gi[p2 + 256 + k];
        }
        __syncthreads();
    };

    for (int step = 0; step < 512; step += 2) {
        body(step,     gra, gza, gna);
        body(step + 1, grb, gzb, gnb);
    }
}

// ---------------------------------------------------------------------------
// Controller h-scan. 16 WGs, 128 threads (2 waves).
// ---------------------------------------------------------------------------
__global__ __launch_bounds__(128, 1) void ctrl_h_scan(
    const float* __restrict__ gie, const float* __restrict__ whh_e,
    const float* __restrict__ bhh_e, float* __restrict__ h_seq)
{
    int b = blockIdx.x, tid = threadIdx.x;
    float4 w[8] = {};
    float bias = 0.f;
    if (tid < 96) {
        const float4* wp = (const float4*)(whh_e + (size_t)tid * 32);
        #pragma unroll
        for (int i = 0; i < 8; ++i) w[i] = wp[i];
        bias = bhh_e[tid];
    }
    __shared__ __align__(16) float hbuf[32];
    __shared__ float ghl[96];
    if (tid < 32) hbuf[tid] = 0.f;

    int pbase = b * TT;
    float g1a = 0.f, g2a = 0.f, g3a = 0.f, g1b = 0.f, g2b = 0.f, g3b = 0.f;
    float hreg = 0.f;
    if (tid < 32) {
        size_t p0 = (size_t)pbase * 96, p1 = (size_t)(pbase + 1) * 96;
        g1a = gie[p0 + tid]; g2a = gie[p0 + 32 + tid]; g3a = gie[p0 + 64 + tid];
        g1b = gie[p1 + tid]; g2b = gie[p1 + 32 + tid]; g3b = gie[p1 + 64 + tid];
    }
    __syncthreads();

    auto body = [&](int t, float& g1, float& g2, float& g3) {
        if (tid < 96) {
            const float4* hv = (const float4*)hbuf;
            float gh = bias;
            #pragma unroll
            for (int i = 0; i < 8; ++i) gh += dot4(w[i], hv[i]);
            ghl[tid] = gh;
        }
        __syncthreads();
        if (tid < 32) {
            float r = sigmoid_(g1 + ghl[tid]);
            float z = sigmoid_(g2 + ghl[32 + tid]);
            float n = tanh_(g3 + r * ghl[64 + tid]);
            float hn = (1.f - z) * n + z * hreg;
            hreg = hn;
            hbuf[tid] = hn;
            h_seq[(size_t)(pbase + t) * 32 + tid] = hn;
            int t2 = (t + 2 < 512) ? t + 2 : t;
            size_t p2 = (size_t)(pbase + t2) * 96;
            g1 = gie[p2 + tid]; g2 = gie[p2 + 32 + tid]; g3 = gie[p2 + 64 + tid];
        }
        __syncthreads();
    };

    for (int t = 0; t < 512; t += 2) {
        body(t,     g1a, g2a, g3a);
        body(t + 1, g1b, g2b, g3b);
    }
}

// ---------------------------------------------------------------------------
// Controller z/beta scan. 16 WGs, 1 wave, no LDS, no barriers.
// ---------------------------------------------------------------------------
__global__ __launch_bounds__(64, 1) void ctrl_z_scan(
    const float* __restrict__ hid_pre, const float* __restrict__ sw1_w,
    const float* __restrict__ sw2_w, const float* __restrict__ sw2_b,
    const float* __restrict__ eps, const float* __restrict__ mu_o,
    const float* __restrict__ lv_o, float* __restrict__ beta_o, float* __restrict__ z_o)
{
    int b = blockIdx.x, q = threadIdx.x;
    float wz[8];
    #pragma unroll
    for (int x = 0; x < 8; ++x) wz[x] = sw1_w[(size_t)q * 296 + 288 + x];
    float w2 = sw2_w[q];
    float bb = sw2_b[0];
    float zc = 0.f;
    int pbase = b * TT;

    float hpa = hid_pre[(size_t)pbase * 64 + q];
    float hpb = hid_pre[(size_t)(pbase + 1) * 64 + q];
    float mua = 0.f, lva = 0.f, epa = 0.f, mub = 0.f, lvb = 0.f, epb = 0.f;
    if (q < 8) {
        mua = mu_o[pbase * 8 + q]; lva = lv_o[pbase * 8 + q]; epa = eps[pbase * 8 + q];
        mub = mu_o[(pbase + 1) * 8 + q]; lvb = lv_o[(pbase + 1) * 8 + q]; epb = eps[(pbase + 1) * 8 + q];
    }

    auto body = [&](int t, float& hp, float& mu, float& lv, float& ep) {
        int p = pbase + t;
        float a = hp;
        #pragma unroll
        for (int x = 0; x < 8; ++x) a += wz[x] * __shfl(zc, x);
        float hid = tanh_(a);
        float prod = w2 * hid;
        #pragma unroll
        for (int m = 32; m >= 1; m >>= 1) prod += __shfl_xor(prod, m);
        float beta = sigmoid_(prod + bb);
        float zn = beta * (mu + __expf(0.5f * lv) * ep) + (1.f - beta) * zc;
        zc = zn;                      // meaningful in lanes 0-7 only
        if (q < 8) z_o[p * 8 + q] = zn;
        if (q == 0) beta_o[p] = beta;
        int t2 = (t + 2 < 512) ? t + 2 : t;
        hp = hid_pre[(size_t)(pbase + t2) * 64 + q];
        if (q < 8) {
            mu = mu_o[(pbase + t2) * 8 + q];
            lv = lv_o[(pbase + t2) * 8 + q];
            ep = eps[(pbase + t2) * 8 + q];
        }
    };

    for (int t = 0; t < 512; t += 2) {
        body(t,     hpa, mua, lva, epa);
        body(t + 1, hpb, mub, lvb, epb);
    }
}

// ---------------------------------------------------------------------------
// Decoder hypernet + rank-R perturbation + LayerNorm + head. P=8/WG.
// ---------------------------------------------------------------------------
__global__ __launch_bounds__(256, 3) void decoder_final(
    const float* __restrict__ e_seq, const float* __restrict__ z_o,
    const float* __restrict__ dec1_w, const float* __restrict__ dec1_b,
    const float* __restrict__ dec2_w, const float* __restrict__ dec2_b,
    const float* __restrict__ ln_g, const float* __restrict__ ln_b,
    const float* __restrict__ head_w, const float* __restrict__ head_b,
    float* __restrict__ logits)
{
    __shared__ __align__(16) float e_l[8][256];
    __shared__ __align__(16) float hmid[8][32];
    __shared__ float zl[8][8];
    __shared__ float tmpw[8][16];
    __shared__ __align__(16) float partb[2048];
    __shared__ float red1[8][16];
    __shared__ float red2[8][16];
    __shared__ float stats[8][2];
    int tid = threadIdx.x;
    int p0 = blockIdx.x * 8;

    {
        const float4* eg = (const float4*)(e_seq + (size_t)p0 * 256);
        float4* el4 = (float4*)&e_l[0][0];
        el4[tid] = eg[tid];
        el4[tid + 256] = eg[tid + 256];
        if (tid < 64) ((float*)zl)[tid] = z_o[p0 * 8 + tid];
    }
    __syncthreads();
    {
        int pp = tid >> 5, g = tid & 31;
        float a = dec1_b[g];
        #pragma unroll
        for (int x = 0; x < 8; ++x) a += dec1_w[g * 8 + x] * zl[pp][x];
        hmid[pp][g] = tanh_(a);
    }
    __syncthreads();
    // ---- pass B: tmp[pp][r] = sum_d Bm[d,r]*e[d]
    {
        int r = tid & 15, dgrp = tid >> 4;
        float acc[8];
        #pragma unroll
        for (int pp = 0; pp < 8; ++pp) acc[pp] = 0.f;
        for (int iblk = 0; iblk < 8; ++iblk) {
            float4 wr[2][8]; float wb[2]; int dd[2];
            #pragma unroll
            for (int ii = 0; ii < 2; ++ii) {
                int d = dgrp + 16 * (iblk * 2 + ii);
                dd[ii] = d;
                int row = 4096 + d * 16 + r;
                const float4* wp = (const float4*)(dec2_w + (size_t)row * 32);
                #pragma unroll
                for (int g = 0; g < 8; ++g) wr[ii][g] = wp[g];
                wb[ii] = dec2_b[row];
            }
            #pragma unroll 1
            for (int pp = 0; pp < 8; ++pp) {
                const float4* hv = (const float4*)hmid[pp];
                float b0 = wb[0], b1 = wb[1];
                #pragma unroll
                for (int g = 0; g < 8; ++g) {
                    float4 hh = hv[g];
                    b0 += dot4(wr[0][g], hh);
                    b1 += dot4(wr[1][g], hh);
                }
                acc[pp] += b0 * e_l[pp][dd[0]] + b1 * e_l[pp][dd[1]];
            }
        }
        #pragma unroll
        for (int pp = 0; pp < 8; ++pp) partb[(pp * 16 + r) * 16 + dgrp] = acc[pp];
    }
    __syncthreads();
    if (tid < 128) {
        int pp = tid >> 4, rr = tid & 15;
        float s = 0.f;
        #pragma unroll
        for (int dg = 0; dg < 16; ++dg) s += partb[(pp * 16 + rr) * 16 + dg];
        tmpw[pp][rr] = s;
    }
    __syncthreads();
    // ---- pass A
    {
        int d = tid;
        float po[8];
        #pragma unroll
        for (int pp = 0; pp < 8; ++pp) po[pp] = e_l[pp][d];
        for (int rblk = 0; rblk < 8; ++rblk) {
            float4 wr[2][8]; float wb[2];
            #pragma unroll
            for (int ii = 0; ii < 2; ++ii) {
                int row = d * 16 + rblk * 2 + ii;
                const float4* wp = (const float4*)(dec2_w + (size_t)row * 32);
                #pragma unroll
                for (int g = 0; g < 8; ++g) wr[ii][g] = wp[g];
                wb[ii] = dec2_b[row];
            }
            #pragma unroll 1
            for (int pp = 0; pp < 8; ++pp) {
                const float4* hv = (const float4*)hmid[pp];
                float a0 = wb[0], a1 = wb[1];
                #pragma unroll
                for (int g = 0; g < 8; ++g) {
                    float4 hh = hv[g];
                    a0 += dot4(wr[0][g], hh);
                    a1 += dot4(wr[1][g], hh);
                }
                po[pp] += a0 * tmpw[pp][rblk * 2] + a1 * tmpw[pp][rblk * 2 + 1];
            }
        }
        #pragma unroll
        for (int pp = 0; pp < 8; ++pp) partb[pp * 256 + d] = po[pp];
    }
    __syncthreads();
    if (tid < 128) {
        int pp = tid >> 4, c = tid & 15;
        float s = 0.f, s2 = 0.f;
        #pragma unroll
        for (int i = 0; i < 16; ++i) { float v = partb[pp * 256 + c * 16 + i]; s += v; s2 += v * v; }
        red1[pp][c] = s; red2[pp][c] = s2;
    }
    __syncthreads();
    if (tid < 8) {
        float s = 0.f, s2 = 0.f;
        #pragma unroll
        for (int c = 0; c < 16; ++c) { s += red1[tid][c]; s2 += red2[tid][c]; }
        float mean = s * (1.f / 256.f);
        float var = s2 * (1.f / 256.f) - mean * mean;
        stats[tid][0] = mean;
        stats[tid][1] = rsqrtf(var + 1e-5f);
    }
    __syncthreads();
    {
        int d = tid;
        float g = ln_g[d], bln = ln_b[d];
        #pragma unroll
        for (int pp = 0; pp < 8; ++pp) {
            float v = (partb[pp * 256 + d] - stats[pp][0]) * stats[pp][1];
            partb[pp * 256 + d] = v * g + bln;
        }
    }
    __syncthreads();
    if (tid < 144) {
        int pp = tid / 18, na = tid - pp * 18;
        float a = head_b[na];
        for (int d2 = 0; d2 < 256; ++d2)
            a += partb[pp * 256 + d2] * head_w[na * 256 + d2];
        logits[(size_t)(p0 + pp) * 18 + na] = a;
    }
}

// ---------------------------------------------------------------------------
extern "C" void kernel_launch(void* const* d_in, const int* in_sizes, int n_in,
                              void* d_out, int out_size, void* d_ws, size_t ws_size,
                              hipStream_t stream) {
    (void)in_sizes; (void)n_in; (void)out_size; (void)ws_size;
    const float* e     = (const float*)d_in[0];
    const float* eps   = (const float*)d_in[1];
    const float* wih_f = (const float*)d_in[2];
    const float* whh_f = (const float*)d_in[3];
    const float* bih_f = (const float*)d_in[4];
    const float* bhh_f = (const float*)d_in[5];
    const float* wih_b = (const float*)d_in[6];
    const float* whh_b = (const float*)d_in[7];
    const float* bih_b = (const float*)d_in[8];
    const float* bhh_b = (const float*)d_in[9];
    const float* wih_e = (const float*)d_in[10];
    const float* whh_e = (const float*)d_in[11];
    const float* bih_e = (const float*)d_in[12];
    const float* bhh_e = (const float*)d_in[13];
    const float* mu_w  = (const float*)d_in[14];
    const float* mu_b  = (const float*)d_in[15];
    const float* lv_w  = (const float*)d_in[16];
    const float* lv_b  = (const float*)d_in[17];
    const float* sw1_w = (const float*)d_in[18];
    const float* sw1_b = (const float*)d_in[19];
    const float* sw2_w = (const float*)d_in[20];
    const float* sw2_b = (const float*)d_in[21];
    const float* dec1_w = (const float*)d_in[22];
    const float* dec1_b = (const float*)d_in[23];
    const float* dec2_w = (const float*)d_in[24];
    const float* dec2_b = (const float*)d_in[25];
    const float* ln_g  = (const float*)d_in[26];
    const float* ln_b  = (const float*)d_in[27];
    const float* head_w = (const float*)d_in[28];
    const float* head_b = (const float*)d_in[29];

    float* ws    = (float*)d_ws;
    float* gi_f  = ws;                       // 8192*384
    float* gi_b  = gi_f + 3145728;           // 8192*384
    float* gie   = gi_b + 3145728;           // 8192*96
    float* swe   = gie + 786432;             // 8192*64 (hid_pre)
    float* s_seq = swe + 524288;             // 8192*256
    float* h_seq = s_seq + 2097152;          // 8192*32
    unsigned short* pk = (unsigned short*)(h_seq + 262144);  // 98304 ushorts

    float* out       = (float*)d_out;
    float* out_logit = out;                  // 147456
    float* out_mu    = out + 147456;         // 65536
    float* out_lv    = out + 212992;         // 65536
    float* out_beta  = out + 278528;         // 8192
    float* out_z     = out + 286720;         // 65536

    // pack recurrent weights to bf16 (thread-contiguous layout)
    pack_w<<<384, 256, 0, stream>>>(whh_f, whh_b, pk);
    // input projections (parallel)
    gemm_k<<<dim3(128, 12), 256, 0, stream>>>(e, 256, wih_f, 256, bih_f, gi_f, 384, 384, 0);
    gemm_k<<<dim3(128, 12), 256, 0, stream>>>(e, 256, wih_b, 256, bih_b, gi_b, 384, 384, 0);
    gemm_k<<<dim3(128, 3),  256, 0, stream>>>(e, 256, wih_e, 512, bih_e, gie, 96, 96, 0);
    gemm_k<<<dim3(128, 2),  256, 0, stream>>>(e, 256, sw1_w, 296, sw1_b, swe, 64, 64, 0);
    // bidirectional GRU recurrence (bf16 weight stream)
    gru_seq<<<32, 512, 0, stream>>>(gi_f, gi_b, pk, bhh_f, bhh_b, s_seq);
    // add s-part of controller GRU input projection
    gemm_k<<<dim3(128, 3), 256, 0, stream>>>(s_seq, 256, wih_e + 256, 512, nullptr, gie, 96, 96, 1);
    // controller h scan
    ctrl_h_scan<<<16, 128, 0, stream>>>(gie, whh_e, bhh_e, h_seq);
    // mu / logvar heads + h-part of switching-unit input
    gemm_k<<<dim3(128, 1), 256, 0, stream>>>(h_seq, 32, mu_w, 32, mu_b, out_mu, 8, 8, 0);
    gemm_k<<<dim3(128, 1), 256, 0, stream>>>(h_seq, 32, lv_w, 32, lv_b, out_lv, 8, 8, 0);
    gemm_k<<<dim3(128, 2), 256, 0, stream>>>(h_seq, 32, sw1_w + 256, 296, nullptr, swe, 64, 64, 1);
    // beta / z scan
    ctrl_z_scan<<<16, 64, 0, stream>>>(swe, sw1_w, sw2_w, sw2_b, eps, out_mu, out_lv, out_beta, out_z);
    // decoder hypernet + perturbation + LN + head
    decoder_final<<<1024, 256, 0, stream>>>(e, out_z, dec1_w, dec1_b, dec2_w, dec2_b,
                                            ln_g, ln_b, head_w, head_b, out_logit);
}